// Round 8
// baseline (134.534 us; speedup 1.0000x reference)
//
#include <hip/hip_runtime.h>

#define BB 8
#define CC 128
#define HH 64
#define WW 64
#define NOFF 18

typedef __bf16 bf16x8 __attribute__((ext_vector_type(8)));
typedef float  f32x4  __attribute__((ext_vector_type(4)));
typedef float  f32x2u __attribute__((ext_vector_type(2), aligned(4)));

// ---------------------------------------------------------------------------
// Kernel 1: fused prep (weight->A-frag pack) + NCHW->NHWC transpose.
// ---------------------------------------------------------------------------
__global__ __launch_bounds__(256) void prep_transpose_kernel(
    const float* __restrict__ x, const float* __restrict__ u,
    const float* __restrict__ w, const float* __restrict__ ow,
    __bf16* __restrict__ ct, __bf16* __restrict__ af, __bf16* __restrict__ waf)
{
    const int tid = threadIdx.x;
    if (blockIdx.x < 512) {
        const int id   = blockIdx.x;
        const int b    = id & 7;
        const int y    = id >> 3;
        const int lane = tid & 63;
        const int wv   = tid >> 6;

        __shared__ __align__(16) __bf16 t[64][264];
#pragma unroll
        for (int g = 0; g < 8; ++g) {
            bf16x8 pk;
#pragma unroll
            for (int j = 0; j < 8; ++j) {
                int ic = wv * 64 + g * 8 + j;
                float v = (ic < CC)
                    ? x[((size_t)(b * CC + ic) * HH + y) * WW + lane]
                    : u[((size_t)(b * CC + (ic - CC)) * HH + y) * WW + lane];
                pk[j] = (__bf16)v;
            }
            *(bf16x8*)&t[lane][wv * 64 + g * 8] = pk;
        }
        __syncthreads();

        __bf16* dst = ct + (size_t)(b * HH + y) * WW * 256;
#pragma unroll
        for (int p = 0; p < 8; ++p) {
            int idx = p * 256 + tid;
            int px = idx >> 5, ch = idx & 31;
            *(bf16x8*)(dst + px * 256 + ch * 8) = *(const bf16x8*)&t[px][ch * 8];
        }
    } else {
        int idx = (blockIdx.x - 512) * 256 + tid;
        if (idx < 147456) {
            int j    = idx & 7;
            int lane = (idx >> 3) & 63;
            int ks   = (idx >> 9) & 3;
            int mt2  = (idx >> 11) & 7;
            int k    = idx >> 14;
            int o = mt2 * 16 + (lane & 15);
            int c = ks * 32 + (lane >> 4) * 8 + j;
            af[idx] = (__bf16)w[(o * CC + c) * 9 + k];
        } else if (idx < 147456 + 73728) {
            int t2   = idx - 147456;
            int j    = t2 & 7;
            int lane = (t2 >> 3) & 63;
            int ks   = (t2 >> 9) & 7;
            int mt   = (t2 >> 12) & 1;
            int kk   = t2 >> 13;
            int oc = mt * 16 + (lane & 15);
            int ic = ks * 32 + (lane >> 4) * 8 + j;
            float v = (oc < NOFF) ? ow[(oc * 256 + ic) * 9 + kk] : 0.f;
            waf[t2] = (__bf16)v;
        }
    }
}

// ---------------------------------------------------------------------------
// Kernel 2: FUSED conv+sample+einsum, half-row blocks for 4 blocks/CU.
// Block=(b,h,half): 32 pixels. Grid 1024. LDS 26.6 KB, launch_bounds(256,4).
//  conv: T[34][264] (32 px + x-halo), waves split (mt,nt) 2x2 -> off_lds.
//  fam:  sampT[2][32][136] double-buffered; preload(k+2)/combine(k+1)/mfma(k)
//        pipeline, 1 barrier per tap.
// ---------------------------------------------------------------------------
__global__ __launch_bounds__(256, 4) void fam_fused_kernel(
    const __bf16* __restrict__ ct, const __bf16* __restrict__ waf,
    const __bf16* __restrict__ af, const float* __restrict__ ob,
    const float* __restrict__ bias, float* __restrict__ out)
{
    const int id   = blockIdx.x;
    const int b    = id & 7;
    const int half = (id >> 3) & 1;
    const int h    = id >> 4;
    const int p0   = half * 32;
    const int tid  = threadIdx.x;
    const int lane = tid & 63;
    const int wv   = tid >> 6;
    const int col  = lane & 15;
    const int quad = lane >> 4;

    __shared__ __align__(16) unsigned char smem[24320];
    __shared__ float off_lds[NOFF][32];

    __bf16 (*T)[264] = (__bf16(*)[264])smem;                 // 34 rows used
    __bf16 (*sampT)[32][136] = (__bf16(*)[32][136])smem;     // 2*32*136*2 = 17408 B
    float* s_ax = (float*)(smem + 17408);                    // 9*32 each
    float* s_ay = s_ax + 288;
    float* s_bx = s_ay + 288;
    float* s_by = s_bx + 288;
    int*   s_i0 = (int*)(s_by + 288);
    int*   s_i1 = s_i0 + 288;

    // ================= Stage 1: offset conv (32x32 tile) =================
    {
        const int mt  = wv >> 1;       // oc tile 0..1
        const int ntw = wv & 1;        // pixel tile 0..1
        f32x4 acc = {0.f, 0.f, 0.f, 0.f};
        const bf16x8* wafp = (const bf16x8*)waf;

        for (int kh = 0; kh < 3; ++kh) {
            int y = h - 1 + kh;
            if (y < 0 || y >= HH) continue;       // block-uniform
            __syncthreads();
            const __bf16* row = ct + (size_t)(b * HH + y) * WW * 256;
            // stage 34 columns (px = p0-1 .. p0+32), zeros outside [0,64)
#pragma unroll
            for (int it = 0; it < 5; ++it) {
                int idx = it * 256 + tid;
                if (idx < 34 * 32) {
                    int cl = idx >> 5, ch = idx & 31;
                    int gpx = p0 - 1 + cl;
                    bf16x8 v;
                    if (gpx >= 0 && gpx < WW)
                        v = *(const bf16x8*)(row + gpx * 256 + ch * 8);
                    else {
#pragma unroll
                        for (int j = 0; j < 8; ++j) v[j] = (__bf16)0.f;
                    }
                    *(bf16x8*)&T[cl][ch * 8] = v;
                }
            }
            __syncthreads();

#pragma unroll
            for (int kw = 0; kw < 3; ++kw) {
                int kk = kh * 3 + kw;
                const __bf16* brow = &T[ntw * 16 + col + kw][quad * 8];
#pragma unroll
                for (int ks = 0; ks < 8; ++ks) {
                    bf16x8 bfrag = *(const bf16x8*)(brow + ks * 32);
                    bf16x8 a = wafp[((kk * 2 + mt) * 8 + ks) * 64 + lane];
                    acc = __builtin_amdgcn_mfma_f32_16x16x32_bf16(a, bfrag, acc, 0, 0, 0);
                }
            }
        }

        int pxl = ntw * 16 + col;
#pragma unroll
        for (int r = 0; r < 4; ++r) {
            int oc = mt * 16 + quad * 4 + r;
            if (oc < NOFF) off_lds[oc][pxl] = acc[r] + ob[oc];
        }
    }
    __syncthreads();   // off_lds visible; T region dead

    // ================= Stage 2: bilinear coeffs (32 px x 9 taps) ==========
    for (int t = tid; t < 9 * 32; t += 256) {
        int k  = t >> 5;
        int wq = t & 31;            // local pixel
        int wqg = p0 + wq;          // global pixel
        float dy = off_lds[2 * k][wq];
        float dx = off_lds[2 * k + 1][wq];
        float py = (float)(h - 1 + k / 3) + dy;
        float px = (float)(wqg - 1 + k % 3) + dx;
        float y0f = floorf(py), x0f = floorf(px);
        int y0 = (int)y0f, x0 = (int)x0f;
        float fy = py - y0f, fx = px - x0f;
        bool vy0 = (y0 >= 0) && (y0 < HH);
        bool vy1 = (y0 + 1 >= 0) && (y0 + 1 < HH);
        bool vx0 = (x0 >= 0) && (x0 < WW);
        bool vx1 = (x0 + 1 >= 0) && (x0 + 1 < WW);
        float w00 = (1.f - fy) * (1.f - fx) * ((vy0 && vx0) ? 1.f : 0.f);
        float w01 = (1.f - fy) * fx         * ((vy0 && vx1) ? 1.f : 0.f);
        float w10 = fy * (1.f - fx)         * ((vy1 && vx0) ? 1.f : 0.f);
        float w11 = fy * fx                 * ((vy1 && vx1) ? 1.f : 0.f);
        int y0c = min(max(y0, 0), HH - 1);
        int y1c = min(max(y0 + 1, 0), HH - 1);
        int x0c = min(max(x0, 0), WW - 1);
        int x1c = min(max(x0 + 1, 0), WW - 1);
        int xl  = min(max(x0, 0), WW - 2);
        float ax = ((x0c == xl)     ? w00 : 0.f) + ((x1c == xl)     ? w01 : 0.f);
        float ay = ((x0c == xl + 1) ? w00 : 0.f) + ((x1c == xl + 1) ? w01 : 0.f);
        float bx = ((x0c == xl)     ? w10 : 0.f) + ((x1c == xl)     ? w11 : 0.f);
        float by = ((x0c == xl + 1) ? w10 : 0.f) + ((x1c == xl + 1) ? w11 : 0.f);
        s_ax[k * 32 + wq] = ax; s_ay[k * 32 + wq] = ay;
        s_bx[k * 32 + wq] = bx; s_by[k * 32 + wq] = by;
        s_i0[k * 32 + wq] = y0c * WW + xl;
        s_i1[k * 32 + wq] = y1c * WW + xl;
    }
    __syncthreads();

    // ================= Stage 3: pipelined taps =================
    f32x4 acc[2][2];
#pragma unroll
    for (int mt = 0; mt < 2; ++mt)
#pragma unroll
        for (int nt = 0; nt < 2; ++nt) acc[mt][nt] = (f32x4){0.f, 0.f, 0.f, 0.f};

    const __bf16* ctb = ct + (size_t)b * (HH * WW * 256);
    const bf16x8* afp = (const bf16x8*)af;

    bf16x8 rA[2], rB[2], rC[2], rD[2];

    auto preload = [&](int kk) {
#pragma unroll
        for (int p = 0; p < 2; ++p) {
            int idx = p * 256 + tid;
            int px = idx >> 4, ch = idx & 15;
            const __bf16* r0 = ctb + (size_t)s_i0[kk * 32 + px] * 256 + 128 + ch * 8;
            const __bf16* r1 = ctb + (size_t)s_i1[kk * 32 + px] * 256 + 128 + ch * 8;
            rA[p] = *(const bf16x8*)r0;
            rB[p] = *(const bf16x8*)(r0 + 256);
            rC[p] = *(const bf16x8*)r1;
            rD[p] = *(const bf16x8*)(r1 + 256);
        }
    };
    auto combine = [&](int kk, int buf) {
#pragma unroll
        for (int p = 0; p < 2; ++p) {
            int idx = p * 256 + tid;
            int px = idx >> 4, ch = idx & 15;
            float ax = s_ax[kk * 32 + px], ay = s_ay[kk * 32 + px];
            float bx = s_bx[kk * 32 + px], by = s_by[kk * 32 + px];
            bf16x8 res;
#pragma unroll
            for (int j = 0; j < 8; ++j)
                res[j] = (__bf16)(ax * (float)rA[p][j] + ay * (float)rB[p][j] +
                                  bx * (float)rC[p][j] + by * (float)rD[p][j]);
            *(bf16x8*)&sampT[buf][px][ch * 8] = res;
        }
    };
    auto domfma = [&](int kk, int buf) {
#pragma unroll
        for (int ks = 0; ks < 4; ++ks) {
            bf16x8 a0 = afp[((kk * 8 + wv * 2 + 0) * 4 + ks) * 64 + lane];
            bf16x8 a1 = afp[((kk * 8 + wv * 2 + 1) * 4 + ks) * 64 + lane];
            int crow = ks * 32 + quad * 8;
#pragma unroll
            for (int nt = 0; nt < 2; ++nt) {
                bf16x8 bfrag = *(const bf16x8*)&sampT[buf][nt * 16 + col][crow];
                acc[0][nt] = __builtin_amdgcn_mfma_f32_16x16x32_bf16(
                    a0, bfrag, acc[0][nt], 0, 0, 0);
                acc[1][nt] = __builtin_amdgcn_mfma_f32_16x16x32_bf16(
                    a1, bfrag, acc[1][nt], 0, 0, 0);
            }
        }
    };

    preload(0);
    combine(0, 0);
    preload(1);
    __syncthreads();
    for (int k = 0; k < 9; ++k) {
        domfma(k, k & 1);
        if (k < 8) {
            combine(k + 1, (k + 1) & 1);
            if (k + 2 <= 8) preload(k + 2);
            __syncthreads();
        }
    }

    // ================= Epilogue =================
#pragma unroll
    for (int mt = 0; mt < 2; ++mt) {
#pragma unroll
        for (int r = 0; r < 4; ++r) {
            int o = wv * 32 + mt * 16 + quad * 4 + r;
            float bv = bias[o];
#pragma unroll
            for (int nt = 0; nt < 2; ++nt)
                out[((size_t)(b * CC + o) * HH + h) * WW + p0 + nt * 16 + col] =
                    acc[mt][nt][r] + bv;
        }
    }
}

// ===========================================================================
// Fallback path (proven R5 kernels; needs only 2.8 MB ws).
// ===========================================================================
__global__ __launch_bounds__(256) void prep_kernel(
    const float* __restrict__ w, const float* __restrict__ ow,
    __bf16* __restrict__ af, __bf16* __restrict__ waf)
{
    int idx = blockIdx.x * 256 + threadIdx.x;
    if (idx < 147456) {
        int j    = idx & 7;
        int lane = (idx >> 3) & 63;
        int ks   = (idx >> 9) & 3;
        int mt2  = (idx >> 11) & 7;
        int k    = idx >> 14;
        int o = mt2 * 16 + (lane & 15);
        int c = ks * 32 + (lane >> 4) * 8 + j;
        af[idx] = (__bf16)w[(o * CC + c) * 9 + k];
    } else if (idx < 147456 + 73728) {
        int t    = idx - 147456;
        int j    = t & 7;
        int lane = (t >> 3) & 63;
        int ks   = (t >> 9) & 7;
        int mt   = (t >> 12) & 1;
        int kk   = t >> 13;
        int oc = mt * 16 + (lane & 15);
        int ic = ks * 32 + (lane >> 4) * 8 + j;
        float v = (oc < NOFF) ? ow[(oc * 256 + ic) * 9 + kk] : 0.f;
        waf[t] = (__bf16)v;
    }
}

#define TS 264
__global__ __launch_bounds__(256) void offset_conv_mfma_kernel(
    const float* __restrict__ x, const float* __restrict__ u,
    const __bf16* __restrict__ waf, const float* __restrict__ ob,
    float* __restrict__ off)
{
    const int id   = blockIdx.x;
    const int b    = id & 7;
    const int h    = id >> 3;
    const int tid  = threadIdx.x;
    const int lane = tid & 63;
    const int wv   = tid >> 6;
    const int col  = lane & 15;
    const int quad = lane >> 4;

    __shared__ __align__(16) __bf16 T[66][TS];
    {
        T[0][tid]  = (__bf16)0.f;
        T[65][tid] = (__bf16)0.f;
    }

    f32x4 acc0 = {0.f, 0.f, 0.f, 0.f};
    f32x4 acc1 = {0.f, 0.f, 0.f, 0.f};
    const bf16x8* wafp = (const bf16x8*)waf;

    for (int kh = 0; kh < 3; ++kh) {
        int y = h - 1 + kh;
        if (y < 0 || y >= HH) continue;
        __syncthreads();
        {
            int w2 = lane;
#pragma unroll
            for (int g = 0; g < 8; ++g) {
                bf16x8 pk;
#pragma unroll
                for (int j = 0; j < 8; ++j) {
                    int ic = wv * 64 + g * 8 + j;
                    float v = (ic < CC)
                        ? x[((size_t)(b * CC + ic) * HH + y) * WW + w2]
                        : u[((size_t)(b * CC + (ic - CC)) * HH + y) * WW + w2];
                    pk[j] = (__bf16)v;
                }
                *(bf16x8*)&T[w2 + 1][wv * 64 + g * 8] = pk;
            }
        }
        __syncthreads();

#pragma unroll
        for (int kw = 0; kw < 3; ++kw) {
            int kk = kh * 3 + kw;
            const __bf16* brow = &T[wv * 16 + col + kw][quad * 8];
#pragma unroll
            for (int ks = 0; ks < 8; ++ks) {
                bf16x8 bfrag = *(const bf16x8*)(brow + ks * 32);
                bf16x8 a0 = wafp[((kk * 2 + 0) * 8 + ks) * 64 + lane];
                bf16x8 a1 = wafp[((kk * 2 + 1) * 8 + ks) * 64 + lane];
                acc0 = __builtin_amdgcn_mfma_f32_16x16x32_bf16(a0, bfrag, acc0, 0, 0, 0);
                acc1 = __builtin_amdgcn_mfma_f32_16x16x32_bf16(a1, bfrag, acc1, 0, 0, 0);
            }
        }
    }

    int w2 = wv * 16 + col;
#pragma unroll
    for (int r = 0; r < 4; ++r) {
        int oc = quad * 4 + r;
        off[((size_t)(b * NOFF + oc) * HH + h) * WW + w2] = acc0[r] + ob[oc];
    }
#pragma unroll
    for (int r = 0; r < 4; ++r) {
        int oc = 16 + quad * 4 + r;
        if (oc < NOFF)
            off[((size_t)(b * NOFF + oc) * HH + h) * WW + w2] = acc1[r] + ob[oc];
    }
}

__global__ __launch_bounds__(256) void fam_main_kernel(
    const float* __restrict__ u, const __bf16* __restrict__ af,
    const float* __restrict__ bias, const float* __restrict__ off,
    float* __restrict__ out)
{
    const int id   = blockIdx.x;
    const int b    = id & 7;
    const int h    = id >> 3;
    const int tid  = threadIdx.x;
    const int lane = tid & 63;
    const int wv   = tid >> 6;
    const int col  = lane & 15;
    const int quad = lane >> 4;

    __shared__ __align__(16) __bf16 sampT[64][136];
    __shared__ float s_ax[9][64], s_ay[9][64], s_bx[9][64], s_by[9][64];
    __shared__ int   s_i0[9][64], s_i1[9][64];

    for (int t = tid; t < 9 * 64; t += 256) {
        int k  = t >> 6;
        int wq = t & 63;
        float dy = off[((size_t)(b * NOFF + 2 * k)     * HH + h) * WW + wq];
        float dx = off[((size_t)(b * NOFF + 2 * k + 1) * HH + h) * WW + wq];
        float py = (float)(h - 1 + k / 3) + dy;
        float px = (float)(wq - 1 + k % 3) + dx;
        float y0f = floorf(py), x0f = floorf(px);
        int y0 = (int)y0f, x0 = (int)x0f;
        float fy = py - y0f, fx = px - x0f;
        bool vy0 = (y0 >= 0) && (y0 < HH);
        bool vy1 = (y0 + 1 >= 0) && (y0 + 1 < HH);
        bool vx0 = (x0 >= 0) && (x0 < WW);
        bool vx1 = (x0 + 1 >= 0) && (x0 + 1 < WW);
        float w00 = (1.f - fy) * (1.f - fx) * ((vy0 && vx0) ? 1.f : 0.f);
        float w01 = (1.f - fy) * fx         * ((vy0 && vx1) ? 1.f : 0.f);
        float w10 = fy * (1.f - fx)         * ((vy1 && vx0) ? 1.f : 0.f);
        float w11 = fy * fx                 * ((vy1 && vx1) ? 1.f : 0.f);
        int y0c = min(max(y0, 0), HH - 1);
        int y1c = min(max(y0 + 1, 0), HH - 1);
        int x0c = min(max(x0, 0), WW - 1);
        int x1c = min(max(x0 + 1, 0), WW - 1);
        int xl  = min(max(x0, 0), WW - 2);
        float ax = ((x0c == xl)     ? w00 : 0.f) + ((x1c == xl)     ? w01 : 0.f);
        float ay = ((x0c == xl + 1) ? w00 : 0.f) + ((x1c == xl + 1) ? w01 : 0.f);
        float bx = ((x0c == xl)     ? w10 : 0.f) + ((x1c == xl)     ? w11 : 0.f);
        float by = ((x0c == xl + 1) ? w10 : 0.f) + ((x1c == xl + 1) ? w11 : 0.f);
        s_ax[k][wq] = ax; s_ay[k][wq] = ay;
        s_bx[k][wq] = bx; s_by[k][wq] = by;
        s_i0[k][wq] = y0c * WW + xl;
        s_i1[k][wq] = y1c * WW + xl;
    }
    __syncthreads();

    f32x4 acc[2][4];
#pragma unroll
    for (int mt = 0; mt < 2; ++mt)
#pragma unroll
        for (int nt = 0; nt < 4; ++nt) acc[mt][nt] = (f32x4){0.f, 0.f, 0.f, 0.f};

    const float* ub = u + (size_t)b * (CC * HH * WW);
    const bf16x8* afp = (const bf16x8*)af;

    for (int k = 0; k < 9; ++k) {
        {
            float ax = s_ax[k][lane], ay = s_ay[k][lane];
            float bx = s_bx[k][lane], by = s_by[k][lane];
            int   i0 = s_i0[k][lane], i1 = s_i1[k][lane];
#pragma unroll 4
            for (int g = 0; g < 4; ++g) {
                bf16x8 pk;
#pragma unroll
                for (int j = 0; j < 8; ++j) {
                    const float* up = ub + (size_t)(wv * 32 + g * 8 + j) * (HH * WW);
                    f32x2u r0 = *(const f32x2u*)(up + i0);
                    f32x2u r1 = *(const f32x2u*)(up + i1);
                    float v = ax * r0.x + ay * r0.y + bx * r1.x + by * r1.y;
                    pk[j] = (__bf16)v;
                }
                *(bf16x8*)&sampT[lane][wv * 32 + g * 8] = pk;
            }
        }
        __syncthreads();

#pragma unroll
        for (int ks = 0; ks < 4; ++ks) {
            bf16x8 a0 = afp[((k * 8 + wv * 2 + 0) * 4 + ks) * 64 + lane];
            bf16x8 a1 = afp[((k * 8 + wv * 2 + 1) * 4 + ks) * 64 + lane];
            int crow = ks * 32 + quad * 8;
#pragma unroll
            for (int nt = 0; nt < 4; ++nt) {
                bf16x8 bfrag = *(const bf16x8*)&sampT[nt * 16 + col][crow];
                acc[0][nt] = __builtin_amdgcn_mfma_f32_16x16x32_bf16(
                    a0, bfrag, acc[0][nt], 0, 0, 0);
                acc[1][nt] = __builtin_amdgcn_mfma_f32_16x16x32_bf16(
                    a1, bfrag, acc[1][nt], 0, 0, 0);
            }
        }
        __syncthreads();
    }

#pragma unroll
    for (int mt = 0; mt < 2; ++mt) {
#pragma unroll
        for (int r = 0; r < 4; ++r) {
            int o = wv * 32 + mt * 16 + quad * 4 + r;
            float bv = bias[o];
#pragma unroll
            for (int nt = 0; nt < 4; ++nt)
                out[((size_t)(b * CC + o) * HH + h) * WW + nt * 16 + col] =
                    acc[mt][nt][r] + bv;
        }
    }
}

extern "C" void kernel_launch(void* const* d_in, const int* in_sizes, int n_in,
                              void* d_out, int out_size, void* d_ws, size_t ws_size,
                              hipStream_t stream) {
    const float* x    = (const float*)d_in[0];
    const float* u    = (const float*)d_in[1];
    const float* wgt  = (const float*)d_in[2];
    const float* bias = (const float*)d_in[3];
    const float* ow   = (const float*)d_in[4];
    const float* ob   = (const float*)d_in[5];
    float* out = (float*)d_out;

    // Workspace layout (element-typed arithmetic only):
    float*  off = (float*)d_ws;                                  // 2,359,296 B (fallback only)
    __bf16* af  = (__bf16*)(off + (size_t)BB * NOFF * HH * WW);  //   294,912 B
    __bf16* waf = af + 147456;                                   //   147,456 B
    __bf16* ct  = waf + 73728;                                   // 16,777,216 B (fast path)
    const size_t need_fast = 2359296 + 294912 + 147456 + (size_t)BB * HH * WW * 256 * 2;

    if (ws_size >= need_fast) {
        hipLaunchKernelGGL(prep_transpose_kernel, dim3(1376), dim3(256), 0, stream,
                           x, u, wgt, ow, ct, af, waf);
        hipLaunchKernelGGL(fam_fused_kernel, dim3(1024), dim3(256), 0, stream,
                           ct, waf, af, ob, bias, out);
    } else {
        hipLaunchKernelGGL(prep_kernel, dim3(864), dim3(256), 0, stream,
                           wgt, ow, af, waf);
        hipLaunchKernelGGL(offset_conv_mfma_kernel, dim3(512), dim3(256), 0, stream,
                           x, u, waf, ob, off);
        hipLaunchKernelGGL(fam_main_kernel, dim3(512), dim3(256), 0, stream,
                           u, af, bias, off, out);
    }
}

// Round 9
// 126.348 us; speedup vs baseline: 1.0648x; 1.0648x over previous
//
#include <hip/hip_runtime.h>

#define BB 8
#define CC 128
#define HH 64
#define WW 64
#define NOFF 18

typedef __bf16 bf16x8 __attribute__((ext_vector_type(8)));
typedef float  f32x4  __attribute__((ext_vector_type(4)));
typedef float  f32x2u __attribute__((ext_vector_type(2), aligned(4)));

// ---------------------------------------------------------------------------
// Kernel 1: fused prep (weight->A-frag pack) + NCHW->NHWC transpose.
// ---------------------------------------------------------------------------
__global__ __launch_bounds__(256) void prep_transpose_kernel(
    const float* __restrict__ x, const float* __restrict__ u,
    const float* __restrict__ w, const float* __restrict__ ow,
    __bf16* __restrict__ ct, __bf16* __restrict__ af, __bf16* __restrict__ waf)
{
    const int tid = threadIdx.x;
    if (blockIdx.x < 512) {
        const int id   = blockIdx.x;
        const int b    = id & 7;
        const int y    = id >> 3;
        const int lane = tid & 63;
        const int wv   = tid >> 6;

        __shared__ __align__(16) __bf16 t[64][264];
#pragma unroll
        for (int g = 0; g < 8; ++g) {
            bf16x8 pk;
#pragma unroll
            for (int j = 0; j < 8; ++j) {
                int ic = wv * 64 + g * 8 + j;
                float v = (ic < CC)
                    ? x[((size_t)(b * CC + ic) * HH + y) * WW + lane]
                    : u[((size_t)(b * CC + (ic - CC)) * HH + y) * WW + lane];
                pk[j] = (__bf16)v;
            }
            *(bf16x8*)&t[lane][wv * 64 + g * 8] = pk;
        }
        __syncthreads();

        __bf16* dst = ct + (size_t)(b * HH + y) * WW * 256;
#pragma unroll
        for (int p = 0; p < 8; ++p) {
            int idx = p * 256 + tid;
            int px = idx >> 5, ch = idx & 31;
            *(bf16x8*)(dst + px * 256 + ch * 8) = *(const bf16x8*)&t[px][ch * 8];
        }
    } else {
        int idx = (blockIdx.x - 512) * 256 + tid;
        if (idx < 147456) {
            int j    = idx & 7;
            int lane = (idx >> 3) & 63;
            int ks   = (idx >> 9) & 3;
            int mt2  = (idx >> 11) & 7;
            int k    = idx >> 14;
            int o = mt2 * 16 + (lane & 15);
            int c = ks * 32 + (lane >> 4) * 8 + j;
            af[idx] = (__bf16)w[(o * CC + c) * 9 + k];
        } else if (idx < 147456 + 73728) {
            int t2   = idx - 147456;
            int j    = t2 & 7;
            int lane = (t2 >> 3) & 63;
            int ks   = (t2 >> 9) & 7;
            int mt   = (t2 >> 12) & 1;
            int kk   = t2 >> 13;
            int oc = mt * 16 + (lane & 15);
            int ic = ks * 32 + (lane >> 4) * 8 + j;
            float v = (oc < NOFF) ? ow[(oc * 256 + ic) * 9 + kk] : 0.f;
            waf[t2] = (__bf16)v;
        }
    }
}

// ---------------------------------------------------------------------------
// Kernel 2: FUSED conv+sample+einsum. Block=(b,h), 64 px (R7 tiling).
//  R9: (a) A-frag register double-buffer — tap k's A-frags loaded one tap
//      ahead (first set at kernel entry, hidden behind conv), so the post-
//      barrier critical path starts at MFMA, not at an L2 load;
//      (b) tap rotation k0=id%9 to decorrelate co-resident blocks' gathers.
// ---------------------------------------------------------------------------
__global__ __launch_bounds__(256, 2) void fam_fused_kernel(
    const __bf16* __restrict__ ct, const __bf16* __restrict__ waf,
    const __bf16* __restrict__ af, const float* __restrict__ ob,
    const float* __restrict__ bias, float* __restrict__ out)
{
    const int id   = blockIdx.x;
    const int b    = id & 7;
    const int h    = id >> 3;
    const int tid  = threadIdx.x;
    const int lane = tid & 63;
    const int wv   = tid >> 6;
    const int col  = lane & 15;
    const int quad = lane >> 4;

    __shared__ __align__(16) unsigned char smem[48640];
    __shared__ float off_lds[NOFF][64];

    __bf16 (*T)[264] = (__bf16(*)[264])smem;               // conv view, 66 rows
    __bf16 (*sampT)[64][136] = (__bf16(*)[64][136])smem;   // 2*64*136*2 = 34816 B
    float* s_ax = (float*)(smem + 34816);
    float* s_ay = s_ax + 576;
    float* s_bx = s_ay + 576;
    float* s_by = s_bx + 576;
    int*   s_i0 = (int*)(s_by + 576);
    int*   s_i1 = s_i0 + 576;

    const bf16x8* afp = (const bf16x8*)af;
    const int k0 = id % 9;          // tap rotation phase

    // A-frag double buffer; first set issued NOW (hidden behind conv).
    bf16x8 aBuf[2][8];
    auto load_a = [&](int kk, int pb) {
#pragma unroll
        for (int ks = 0; ks < 4; ++ks) {
            aBuf[pb][ks * 2 + 0] = afp[((kk * 8 + wv * 2 + 0) * 4 + ks) * 64 + lane];
            aBuf[pb][ks * 2 + 1] = afp[((kk * 8 + wv * 2 + 1) * 4 + ks) * 64 + lane];
        }
    };
    load_a(k0, 0);

    // ================= Stage 1: offset conv =================
    {
        T[0][tid]  = (__bf16)0.f;
        T[65][tid] = (__bf16)0.f;

        f32x4 acc0 = {0.f, 0.f, 0.f, 0.f};
        f32x4 acc1 = {0.f, 0.f, 0.f, 0.f};
        const bf16x8* wafp = (const bf16x8*)waf;

        for (int kh = 0; kh < 3; ++kh) {
            int y = h - 1 + kh;
            if (y < 0 || y >= HH) continue;       // block-uniform
            __syncthreads();
            const __bf16* row = ct + (size_t)(b * HH + y) * WW * 256;
#pragma unroll
            for (int p = 0; p < 8; ++p) {
                int idx = p * 256 + tid;
                int px = idx >> 5, ch = idx & 31;
                *(bf16x8*)&T[px + 1][ch * 8] =
                    *(const bf16x8*)(row + px * 256 + ch * 8);
            }
            __syncthreads();

#pragma unroll
            for (int kw = 0; kw < 3; ++kw) {
                int kk = kh * 3 + kw;
                const __bf16* brow = &T[wv * 16 + col + kw][quad * 8];
#pragma unroll
                for (int ks = 0; ks < 8; ++ks) {
                    bf16x8 bfrag = *(const bf16x8*)(brow + ks * 32);
                    bf16x8 a0 = wafp[((kk * 2 + 0) * 8 + ks) * 64 + lane];
                    bf16x8 a1 = wafp[((kk * 2 + 1) * 8 + ks) * 64 + lane];
                    acc0 = __builtin_amdgcn_mfma_f32_16x16x32_bf16(a0, bfrag, acc0, 0, 0, 0);
                    acc1 = __builtin_amdgcn_mfma_f32_16x16x32_bf16(a1, bfrag, acc1, 0, 0, 0);
                }
            }
        }

        int w2 = wv * 16 + col;
#pragma unroll
        for (int r = 0; r < 4; ++r)
            off_lds[quad * 4 + r][w2] = acc0[r] + ob[quad * 4 + r];
#pragma unroll
        for (int r = 0; r < 4; ++r) {
            int oc = 16 + quad * 4 + r;
            if (oc < NOFF) off_lds[oc][w2] = acc1[r] + ob[oc];
        }
    }
    __syncthreads();

    // ================= Stage 2: bilinear coeffs =================
    for (int t = tid; t < 9 * 64; t += 256) {
        int k  = t >> 6;
        int wq = t & 63;
        float dy = off_lds[2 * k][wq];
        float dx = off_lds[2 * k + 1][wq];
        float py = (float)(h - 1 + k / 3) + dy;
        float px = (float)(wq - 1 + k % 3) + dx;
        float y0f = floorf(py), x0f = floorf(px);
        int y0 = (int)y0f, x0 = (int)x0f;
        float fy = py - y0f, fx = px - x0f;
        bool vy0 = (y0 >= 0) && (y0 < HH);
        bool vy1 = (y0 + 1 >= 0) && (y0 + 1 < HH);
        bool vx0 = (x0 >= 0) && (x0 < WW);
        bool vx1 = (x0 + 1 >= 0) && (x0 + 1 < WW);
        float w00 = (1.f - fy) * (1.f - fx) * ((vy0 && vx0) ? 1.f : 0.f);
        float w01 = (1.f - fy) * fx         * ((vy0 && vx1) ? 1.f : 0.f);
        float w10 = fy * (1.f - fx)         * ((vy1 && vx0) ? 1.f : 0.f);
        float w11 = fy * fx                 * ((vy1 && vx1) ? 1.f : 0.f);
        int y0c = min(max(y0, 0), HH - 1);
        int y1c = min(max(y0 + 1, 0), HH - 1);
        int x0c = min(max(x0, 0), WW - 1);
        int x1c = min(max(x0 + 1, 0), WW - 1);
        int xl  = min(max(x0, 0), WW - 2);
        float ax = ((x0c == xl)     ? w00 : 0.f) + ((x1c == xl)     ? w01 : 0.f);
        float ay = ((x0c == xl + 1) ? w00 : 0.f) + ((x1c == xl + 1) ? w01 : 0.f);
        float bx = ((x0c == xl)     ? w10 : 0.f) + ((x1c == xl)     ? w11 : 0.f);
        float by = ((x0c == xl + 1) ? w10 : 0.f) + ((x1c == xl + 1) ? w11 : 0.f);
        s_ax[k * 64 + wq] = ax; s_ay[k * 64 + wq] = ay;
        s_bx[k * 64 + wq] = bx; s_by[k * 64 + wq] = by;
        s_i0[k * 64 + wq] = y0c * WW + xl;
        s_i1[k * 64 + wq] = y1c * WW + xl;
    }
    __syncthreads();

    // ================= Stage 3: pipelined taps (rotated) =================
    f32x4 acc[2][4];
#pragma unroll
    for (int mt = 0; mt < 2; ++mt)
#pragma unroll
        for (int nt = 0; nt < 4; ++nt) acc[mt][nt] = (f32x4){0.f, 0.f, 0.f, 0.f};

    const __bf16* ctb = ct + (size_t)b * (HH * WW * 256);
    bf16x8 rA[4], rB[4], rC[4], rD[4];

    auto preload = [&](int kk) {
#pragma unroll
        for (int p = 0; p < 4; ++p) {
            int idx = p * 256 + tid;
            int px = idx >> 4, ch = idx & 15;
            const __bf16* r0 = ctb + (size_t)s_i0[kk * 64 + px] * 256 + 128 + ch * 8;
            const __bf16* r1 = ctb + (size_t)s_i1[kk * 64 + px] * 256 + 128 + ch * 8;
            rA[p] = *(const bf16x8*)r0;
            rB[p] = *(const bf16x8*)(r0 + 256);
            rC[p] = *(const bf16x8*)r1;
            rD[p] = *(const bf16x8*)(r1 + 256);
        }
    };
    auto combine = [&](int kk, int buf) {
#pragma unroll
        for (int p = 0; p < 4; ++p) {
            int idx = p * 256 + tid;
            int px = idx >> 4, ch = idx & 15;
            float ax = s_ax[kk * 64 + px], ay = s_ay[kk * 64 + px];
            float bx = s_bx[kk * 64 + px], by = s_by[kk * 64 + px];
            bf16x8 res;
#pragma unroll
            for (int j = 0; j < 8; ++j)
                res[j] = (__bf16)(ax * (float)rA[p][j] + ay * (float)rB[p][j] +
                                  bx * (float)rC[p][j] + by * (float)rD[p][j]);
            *(bf16x8*)&sampT[buf][px][ch * 8] = res;
        }
    };
    auto domfma = [&](int pb) {
#pragma unroll
        for (int ks = 0; ks < 4; ++ks) {
            int crow = ks * 32 + quad * 8;
#pragma unroll
            for (int nt = 0; nt < 4; ++nt) {
                bf16x8 bfrag = *(const bf16x8*)&sampT[pb][nt * 16 + col][crow];
                acc[0][nt] = __builtin_amdgcn_mfma_f32_16x16x32_bf16(
                    aBuf[pb][ks * 2 + 0], bfrag, acc[0][nt], 0, 0, 0);
                acc[1][nt] = __builtin_amdgcn_mfma_f32_16x16x32_bf16(
                    aBuf[pb][ks * 2 + 1], bfrag, acc[1][nt], 0, 0, 0);
            }
        }
    };

    // i -> tap kk = (k0 + i) % 9; buffers indexed by i&1.
    {
        int k1 = (k0 + 1 >= 9) ? k0 - 8 : k0 + 1;
        preload(k0);
        combine(k0, 0);
        preload(k1);
        __syncthreads();
    }
#pragma unroll
    for (int i = 0; i < 9; ++i) {
        domfma(i & 1);
        if (i < 8) {
            int kn = k0 + i + 1; if (kn >= 9) kn -= 9;   // tap for iter i+1
            load_a(kn, (i + 1) & 1);                      // A-frags one tap ahead
            combine(kn, (i + 1) & 1);
            if (i + 2 <= 8) {
                int kp = k0 + i + 2; if (kp >= 9) kp -= 9;
                preload(kp);
            }
            __syncthreads();
        }
    }

    // ================= Epilogue =================
#pragma unroll
    for (int mt = 0; mt < 2; ++mt) {
#pragma unroll
        for (int r = 0; r < 4; ++r) {
            int o = wv * 32 + mt * 16 + quad * 4 + r;
            float bv = bias[o];
#pragma unroll
            for (int nt = 0; nt < 4; ++nt)
                out[((size_t)(b * CC + o) * HH + h) * WW + nt * 16 + col] =
                    acc[mt][nt][r] + bv;
        }
    }
}

// ===========================================================================
// Fallback path (proven R5 kernels; needs only 2.8 MB ws).
// ===========================================================================
__global__ __launch_bounds__(256) void prep_kernel(
    const float* __restrict__ w, const float* __restrict__ ow,
    __bf16* __restrict__ af, __bf16* __restrict__ waf)
{
    int idx = blockIdx.x * 256 + threadIdx.x;
    if (idx < 147456) {
        int j    = idx & 7;
        int lane = (idx >> 3) & 63;
        int ks   = (idx >> 9) & 3;
        int mt2  = (idx >> 11) & 7;
        int k    = idx >> 14;
        int o = mt2 * 16 + (lane & 15);
        int c = ks * 32 + (lane >> 4) * 8 + j;
        af[idx] = (__bf16)w[(o * CC + c) * 9 + k];
    } else if (idx < 147456 + 73728) {
        int t    = idx - 147456;
        int j    = t & 7;
        int lane = (t >> 3) & 63;
        int ks   = (t >> 9) & 7;
        int mt   = (t >> 12) & 1;
        int kk   = t >> 13;
        int oc = mt * 16 + (lane & 15);
        int ic = ks * 32 + (lane >> 4) * 8 + j;
        float v = (oc < NOFF) ? ow[(oc * 256 + ic) * 9 + kk] : 0.f;
        waf[t] = (__bf16)v;
    }
}

#define TS 264
__global__ __launch_bounds__(256) void offset_conv_mfma_kernel(
    const float* __restrict__ x, const float* __restrict__ u,
    const __bf16* __restrict__ waf, const float* __restrict__ ob,
    float* __restrict__ off)
{
    const int id   = blockIdx.x;
    const int b    = id & 7;
    const int h    = id >> 3;
    const int tid  = threadIdx.x;
    const int lane = tid & 63;
    const int wv   = tid >> 6;
    const int col  = lane & 15;
    const int quad = lane >> 4;

    __shared__ __align__(16) __bf16 T[66][TS];
    {
        T[0][tid]  = (__bf16)0.f;
        T[65][tid] = (__bf16)0.f;
    }

    f32x4 acc0 = {0.f, 0.f, 0.f, 0.f};
    f32x4 acc1 = {0.f, 0.f, 0.f, 0.f};
    const bf16x8* wafp = (const bf16x8*)waf;

    for (int kh = 0; kh < 3; ++kh) {
        int y = h - 1 + kh;
        if (y < 0 || y >= HH) continue;
        __syncthreads();
        {
            int w2 = lane;
#pragma unroll
            for (int g = 0; g < 8; ++g) {
                bf16x8 pk;
#pragma unroll
                for (int j = 0; j < 8; ++j) {
                    int ic = wv * 64 + g * 8 + j;
                    float v = (ic < CC)
                        ? x[((size_t)(b * CC + ic) * HH + y) * WW + w2]
                        : u[((size_t)(b * CC + (ic - CC)) * HH + y) * WW + w2];
                    pk[j] = (__bf16)v;
                }
                *(bf16x8*)&T[w2 + 1][wv * 64 + g * 8] = pk;
            }
        }
        __syncthreads();

#pragma unroll
        for (int kw = 0; kw < 3; ++kw) {
            int kk = kh * 3 + kw;
            const __bf16* brow = &T[wv * 16 + col + kw][quad * 8];
#pragma unroll
            for (int ks = 0; ks < 8; ++ks) {
                bf16x8 bfrag = *(const bf16x8*)(brow + ks * 32);
                bf16x8 a0 = wafp[((kk * 2 + 0) * 8 + ks) * 64 + lane];
                bf16x8 a1 = wafp[((kk * 2 + 1) * 8 + ks) * 64 + lane];
                acc0 = __builtin_amdgcn_mfma_f32_16x16x32_bf16(a0, bfrag, acc0, 0, 0, 0);
                acc1 = __builtin_amdgcn_mfma_f32_16x16x32_bf16(a1, bfrag, acc1, 0, 0, 0);
            }
        }
    }

    int w2 = wv * 16 + col;
#pragma unroll
    for (int r = 0; r < 4; ++r) {
        int oc = quad * 4 + r;
        off[((size_t)(b * NOFF + oc) * HH + h) * WW + w2] = acc0[r] + ob[oc];
    }
#pragma unroll
    for (int r = 0; r < 4; ++r) {
        int oc = 16 + quad * 4 + r;
        if (oc < NOFF)
            off[((size_t)(b * NOFF + oc) * HH + h) * WW + w2] = acc1[r] + ob[oc];
    }
}

__global__ __launch_bounds__(256) void fam_main_kernel(
    const float* __restrict__ u, const __bf16* __restrict__ af,
    const float* __restrict__ bias, const float* __restrict__ off,
    float* __restrict__ out)
{
    const int id   = blockIdx.x;
    const int b    = id & 7;
    const int h    = id >> 3;
    const int tid  = threadIdx.x;
    const int lane = tid & 63;
    const int wv   = tid >> 6;
    const int col  = lane & 15;
    const int quad = lane >> 4;

    __shared__ __align__(16) __bf16 sampT[64][136];
    __shared__ float s_ax[9][64], s_ay[9][64], s_bx[9][64], s_by[9][64];
    __shared__ int   s_i0[9][64], s_i1[9][64];

    for (int t = tid; t < 9 * 64; t += 256) {
        int k  = t >> 6;
        int wq = t & 63;
        float dy = off[((size_t)(b * NOFF + 2 * k)     * HH + h) * WW + wq];
        float dx = off[((size_t)(b * NOFF + 2 * k + 1) * HH + h) * WW + wq];
        float py = (float)(h - 1 + k / 3) + dy;
        float px = (float)(wq - 1 + k % 3) + dx;
        float y0f = floorf(py), x0f = floorf(px);
        int y0 = (int)y0f, x0 = (int)x0f;
        float fy = py - y0f, fx = px - x0f;
        bool vy0 = (y0 >= 0) && (y0 < HH);
        bool vy1 = (y0 + 1 >= 0) && (y0 + 1 < HH);
        bool vx0 = (x0 >= 0) && (x0 < WW);
        bool vx1 = (x0 + 1 >= 0) && (x0 + 1 < WW);
        float w00 = (1.f - fy) * (1.f - fx) * ((vy0 && vx0) ? 1.f : 0.f);
        float w01 = (1.f - fy) * fx         * ((vy0 && vx1) ? 1.f : 0.f);
        float w10 = fy * (1.f - fx)         * ((vy1 && vx0) ? 1.f : 0.f);
        float w11 = fy * fx                 * ((vy1 && vx1) ? 1.f : 0.f);
        int y0c = min(max(y0, 0), HH - 1);
        int y1c = min(max(y0 + 1, 0), HH - 1);
        int x0c = min(max(x0, 0), WW - 1);
        int x1c = min(max(x0 + 1, 0), WW - 1);
        int xl  = min(max(x0, 0), WW - 2);
        float ax = ((x0c == xl)     ? w00 : 0.f) + ((x1c == xl)     ? w01 : 0.f);
        float ay = ((x0c == xl + 1) ? w00 : 0.f) + ((x1c == xl + 1) ? w01 : 0.f);
        float bx = ((x0c == xl)     ? w10 : 0.f) + ((x1c == xl)     ? w11 : 0.f);
        float by = ((x0c == xl + 1) ? w10 : 0.f) + ((x1c == xl + 1) ? w11 : 0.f);
        s_ax[k][wq] = ax; s_ay[k][wq] = ay;
        s_bx[k][wq] = bx; s_by[k][wq] = by;
        s_i0[k][wq] = y0c * WW + xl;
        s_i1[k][wq] = y1c * WW + xl;
    }
    __syncthreads();

    f32x4 acc[2][4];
#pragma unroll
    for (int mt = 0; mt < 2; ++mt)
#pragma unroll
        for (int nt = 0; nt < 4; ++nt) acc[mt][nt] = (f32x4){0.f, 0.f, 0.f, 0.f};

    const float* ub = u + (size_t)b * (CC * HH * WW);
    const bf16x8* afp = (const bf16x8*)af;

    for (int k = 0; k < 9; ++k) {
        {
            float ax = s_ax[k][lane], ay = s_ay[k][lane];
            float bx = s_bx[k][lane], by = s_by[k][lane];
            int   i0 = s_i0[k][lane], i1 = s_i1[k][lane];
#pragma unroll 4
            for (int g = 0; g < 4; ++g) {
                bf16x8 pk;
#pragma unroll
                for (int j = 0; j < 8; ++j) {
                    const float* up = ub + (size_t)(wv * 32 + g * 8 + j) * (HH * WW);
                    f32x2u r0 = *(const f32x2u*)(up + i0);
                    f32x2u r1 = *(const f32x2u*)(up + i1);
                    float v = ax * r0.x + ay * r0.y + bx * r1.x + by * r1.y;
                    pk[j] = (__bf16)v;
                }
                *(bf16x8*)&sampT[lane][wv * 32 + g * 8] = pk;
            }
        }
        __syncthreads();

#pragma unroll
        for (int ks = 0; ks < 4; ++ks) {
            bf16x8 a0 = afp[((k * 8 + wv * 2 + 0) * 4 + ks) * 64 + lane];
            bf16x8 a1 = afp[((k * 8 + wv * 2 + 1) * 4 + ks) * 64 + lane];
            int crow = ks * 32 + quad * 8;
#pragma unroll
            for (int nt = 0; nt < 4; ++nt) {
                bf16x8 bfrag = *(const bf16x8*)&sampT[nt * 16 + col][crow];
                acc[0][nt] = __builtin_amdgcn_mfma_f32_16x16x32_bf16(
                    a0, bfrag, acc[0][nt], 0, 0, 0);
                acc[1][nt] = __builtin_amdgcn_mfma_f32_16x16x32_bf16(
                    a1, bfrag, acc[1][nt], 0, 0, 0);
            }
        }
        __syncthreads();
    }

#pragma unroll
    for (int mt = 0; mt < 2; ++mt) {
#pragma unroll
        for (int r = 0; r < 4; ++r) {
            int o = wv * 32 + mt * 16 + quad * 4 + r;
            float bv = bias[o];
#pragma unroll
            for (int nt = 0; nt < 4; ++nt)
                out[((size_t)(b * CC + o) * HH + h) * WW + nt * 16 + col] =
                    acc[mt][nt][r] + bv;
        }
    }
}

extern "C" void kernel_launch(void* const* d_in, const int* in_sizes, int n_in,
                              void* d_out, int out_size, void* d_ws, size_t ws_size,
                              hipStream_t stream) {
    const float* x    = (const float*)d_in[0];
    const float* u    = (const float*)d_in[1];
    const float* wgt  = (const float*)d_in[2];
    const float* bias = (const float*)d_in[3];
    const float* ow   = (const float*)d_in[4];
    const float* ob   = (const float*)d_in[5];
    float* out = (float*)d_out;

    // Workspace layout (element-typed arithmetic only):
    float*  off = (float*)d_ws;                                  // 2,359,296 B (fallback only)
    __bf16* af  = (__bf16*)(off + (size_t)BB * NOFF * HH * WW);  //   294,912 B
    __bf16* waf = af + 147456;                                   //   147,456 B
    __bf16* ct  = waf + 73728;                                   // 16,777,216 B (fast path)
    const size_t need_fast = 2359296 + 294912 + 147456 + (size_t)BB * HH * WW * 256 * 2;

    if (ws_size >= need_fast) {
        hipLaunchKernelGGL(prep_transpose_kernel, dim3(1376), dim3(256), 0, stream,
                           x, u, wgt, ow, ct, af, waf);
        hipLaunchKernelGGL(fam_fused_kernel, dim3(512), dim3(256), 0, stream,
                           ct, waf, af, ob, bias, out);
    } else {
        hipLaunchKernelGGL(prep_kernel, dim3(864), dim3(256), 0, stream,
                           wgt, ow, af, waf);
        hipLaunchKernelGGL(offset_conv_mfma_kernel, dim3(512), dim3(256), 0, stream,
                           x, u, waf, ob, off);
        hipLaunchKernelGGL(fam_main_kernel, dim3(512), dim3(256), 0, stream,
                           u, af, bias, off, out);
    }
}

// Round 10
// 126.266 us; speedup vs baseline: 1.0655x; 1.0007x over previous
//
#include <hip/hip_runtime.h>

#define BB 8
#define CC 128
#define HH 64
#define WW 64
#define NOFF 18

typedef __bf16 bf16x8 __attribute__((ext_vector_type(8)));
typedef float  f32x4  __attribute__((ext_vector_type(4)));
typedef float  f32x2u __attribute__((ext_vector_type(2), aligned(4)));

// ---------------------------------------------------------------------------
// Kernel 1: fused prep (weight->A-frag pack) + NCHW->NHWC transpose.
// ---------------------------------------------------------------------------
__global__ __launch_bounds__(256) void prep_transpose_kernel(
    const float* __restrict__ x, const float* __restrict__ u,
    const float* __restrict__ w, const float* __restrict__ ow,
    __bf16* __restrict__ ct, __bf16* __restrict__ af, __bf16* __restrict__ waf)
{
    const int tid = threadIdx.x;
    if (blockIdx.x < 512) {
        const int id   = blockIdx.x;
        const int b    = id & 7;
        const int y    = id >> 3;
        const int lane = tid & 63;
        const int wv   = tid >> 6;

        __shared__ __align__(16) __bf16 t[64][264];
#pragma unroll
        for (int g = 0; g < 8; ++g) {
            bf16x8 pk;
#pragma unroll
            for (int j = 0; j < 8; ++j) {
                int ic = wv * 64 + g * 8 + j;
                float v = (ic < CC)
                    ? x[((size_t)(b * CC + ic) * HH + y) * WW + lane]
                    : u[((size_t)(b * CC + (ic - CC)) * HH + y) * WW + lane];
                pk[j] = (__bf16)v;
            }
            *(bf16x8*)&t[lane][wv * 64 + g * 8] = pk;
        }
        __syncthreads();

        __bf16* dst = ct + (size_t)(b * HH + y) * WW * 256;
#pragma unroll
        for (int p = 0; p < 8; ++p) {
            int idx = p * 256 + tid;
            int px = idx >> 5, ch = idx & 31;
            *(bf16x8*)(dst + px * 256 + ch * 8) = *(const bf16x8*)&t[px][ch * 8];
        }
    } else {
        int idx = (blockIdx.x - 512) * 256 + tid;
        if (idx < 147456) {
            int j    = idx & 7;
            int lane = (idx >> 3) & 63;
            int ks   = (idx >> 9) & 3;
            int mt2  = (idx >> 11) & 7;
            int k    = idx >> 14;
            int o = mt2 * 16 + (lane & 15);
            int c = ks * 32 + (lane >> 4) * 8 + j;
            af[idx] = (__bf16)w[(o * CC + c) * 9 + k];
        } else if (idx < 147456 + 73728) {
            int t2   = idx - 147456;
            int j    = t2 & 7;
            int lane = (t2 >> 3) & 63;
            int ks   = (t2 >> 9) & 7;
            int mt   = (t2 >> 12) & 1;
            int kk   = t2 >> 13;
            int oc = mt * 16 + (lane & 15);
            int ic = ks * 32 + (lane >> 4) * 8 + j;
            float v = (oc < NOFF) ? ow[(oc * 256 + ic) * 9 + kk] : 0.f;
            waf[t2] = (__bf16)v;
        }
    }
}

// ---------------------------------------------------------------------------
// Kernel 2: FUSED conv+sample+einsum. Block=(b,h), 64 px.
//  R10: __launch_bounds__(256,3) -> 3 blocks/CU (LDS 53248*3 = 159744 fits);
//       A-frag prefetch kept but single-buffered (frees 64 VGPR so the
//       168/wave cap for 3-block residency holds). Tap rotation k0=id%9.
// ---------------------------------------------------------------------------
__global__ __launch_bounds__(256, 3) void fam_fused_kernel(
    const __bf16* __restrict__ ct, const __bf16* __restrict__ waf,
    const __bf16* __restrict__ af, const float* __restrict__ ob,
    const float* __restrict__ bias, float* __restrict__ out)
{
    const int id   = blockIdx.x;
    const int b    = id & 7;
    const int h    = id >> 3;
    const int tid  = threadIdx.x;
    const int lane = tid & 63;
    const int wv   = tid >> 6;
    const int col  = lane & 15;
    const int quad = lane >> 4;

    __shared__ __align__(16) unsigned char smem[48640];
    __shared__ float off_lds[NOFF][64];

    __bf16 (*T)[264] = (__bf16(*)[264])smem;               // conv view, 66 rows
    __bf16 (*sampT)[64][136] = (__bf16(*)[64][136])smem;   // 2*64*136*2 = 34816 B
    float* s_ax = (float*)(smem + 34816);
    float* s_ay = s_ax + 576;
    float* s_bx = s_ay + 576;
    float* s_by = s_bx + 576;
    int*   s_i0 = (int*)(s_by + 576);
    int*   s_i1 = s_i0 + 576;

    const bf16x8* afp = (const bf16x8*)af;
    const int k0 = id % 9;          // tap rotation phase

    // A-frag single-buffer prefetch; first set issued NOW (hidden by conv).
    bf16x8 aBuf[8];
    auto load_a = [&](int kk) {
#pragma unroll
        for (int ks = 0; ks < 4; ++ks) {
            aBuf[ks * 2 + 0] = afp[((kk * 8 + wv * 2 + 0) * 4 + ks) * 64 + lane];
            aBuf[ks * 2 + 1] = afp[((kk * 8 + wv * 2 + 1) * 4 + ks) * 64 + lane];
        }
    };
    load_a(k0);

    // ================= Stage 1: offset conv =================
    {
        T[0][tid]  = (__bf16)0.f;
        T[65][tid] = (__bf16)0.f;

        f32x4 acc0 = {0.f, 0.f, 0.f, 0.f};
        f32x4 acc1 = {0.f, 0.f, 0.f, 0.f};
        const bf16x8* wafp = (const bf16x8*)waf;

        for (int kh = 0; kh < 3; ++kh) {
            int y = h - 1 + kh;
            if (y < 0 || y >= HH) continue;       // block-uniform
            __syncthreads();
            const __bf16* row = ct + (size_t)(b * HH + y) * WW * 256;
#pragma unroll
            for (int p = 0; p < 8; ++p) {
                int idx = p * 256 + tid;
                int px = idx >> 5, ch = idx & 31;
                *(bf16x8*)&T[px + 1][ch * 8] =
                    *(const bf16x8*)(row + px * 256 + ch * 8);
            }
            __syncthreads();

#pragma unroll
            for (int kw = 0; kw < 3; ++kw) {
                int kk = kh * 3 + kw;
                const __bf16* brow = &T[wv * 16 + col + kw][quad * 8];
#pragma unroll
                for (int ks = 0; ks < 8; ++ks) {
                    bf16x8 bfrag = *(const bf16x8*)(brow + ks * 32);
                    bf16x8 a0 = wafp[((kk * 2 + 0) * 8 + ks) * 64 + lane];
                    bf16x8 a1 = wafp[((kk * 2 + 1) * 8 + ks) * 64 + lane];
                    acc0 = __builtin_amdgcn_mfma_f32_16x16x32_bf16(a0, bfrag, acc0, 0, 0, 0);
                    acc1 = __builtin_amdgcn_mfma_f32_16x16x32_bf16(a1, bfrag, acc1, 0, 0, 0);
                }
            }
        }

        int w2 = wv * 16 + col;
#pragma unroll
        for (int r = 0; r < 4; ++r)
            off_lds[quad * 4 + r][w2] = acc0[r] + ob[quad * 4 + r];
#pragma unroll
        for (int r = 0; r < 4; ++r) {
            int oc = 16 + quad * 4 + r;
            if (oc < NOFF) off_lds[oc][w2] = acc1[r] + ob[oc];
        }
    }
    __syncthreads();

    // ================= Stage 2: bilinear coeffs =================
    for (int t = tid; t < 9 * 64; t += 256) {
        int k  = t >> 6;
        int wq = t & 63;
        float dy = off_lds[2 * k][wq];
        float dx = off_lds[2 * k + 1][wq];
        float py = (float)(h - 1 + k / 3) + dy;
        float px = (float)(wq - 1 + k % 3) + dx;
        float y0f = floorf(py), x0f = floorf(px);
        int y0 = (int)y0f, x0 = (int)x0f;
        float fy = py - y0f, fx = px - x0f;
        bool vy0 = (y0 >= 0) && (y0 < HH);
        bool vy1 = (y0 + 1 >= 0) && (y0 + 1 < HH);
        bool vx0 = (x0 >= 0) && (x0 < WW);
        bool vx1 = (x0 + 1 >= 0) && (x0 + 1 < WW);
        float w00 = (1.f - fy) * (1.f - fx) * ((vy0 && vx0) ? 1.f : 0.f);
        float w01 = (1.f - fy) * fx         * ((vy0 && vx1) ? 1.f : 0.f);
        float w10 = fy * (1.f - fx)         * ((vy1 && vx0) ? 1.f : 0.f);
        float w11 = fy * fx                 * ((vy1 && vx1) ? 1.f : 0.f);
        int y0c = min(max(y0, 0), HH - 1);
        int y1c = min(max(y0 + 1, 0), HH - 1);
        int x0c = min(max(x0, 0), WW - 1);
        int x1c = min(max(x0 + 1, 0), WW - 1);
        int xl  = min(max(x0, 0), WW - 2);
        float ax = ((x0c == xl)     ? w00 : 0.f) + ((x1c == xl)     ? w01 : 0.f);
        float ay = ((x0c == xl + 1) ? w00 : 0.f) + ((x1c == xl + 1) ? w01 : 0.f);
        float bx = ((x0c == xl)     ? w10 : 0.f) + ((x1c == xl)     ? w11 : 0.f);
        float by = ((x0c == xl + 1) ? w10 : 0.f) + ((x1c == xl + 1) ? w11 : 0.f);
        s_ax[k * 64 + wq] = ax; s_ay[k * 64 + wq] = ay;
        s_bx[k * 64 + wq] = bx; s_by[k * 64 + wq] = by;
        s_i0[k * 64 + wq] = y0c * WW + xl;
        s_i1[k * 64 + wq] = y1c * WW + xl;
    }
    __syncthreads();

    // ================= Stage 3: pipelined taps (rotated) =================
    f32x4 acc[2][4];
#pragma unroll
    for (int mt = 0; mt < 2; ++mt)
#pragma unroll
        for (int nt = 0; nt < 4; ++nt) acc[mt][nt] = (f32x4){0.f, 0.f, 0.f, 0.f};

    const __bf16* ctb = ct + (size_t)b * (HH * WW * 256);
    bf16x8 rA[4], rB[4], rC[4], rD[4];

    auto preload = [&](int kk) {
#pragma unroll
        for (int p = 0; p < 4; ++p) {
            int idx = p * 256 + tid;
            int px = idx >> 4, ch = idx & 15;
            const __bf16* r0 = ctb + (size_t)s_i0[kk * 64 + px] * 256 + 128 + ch * 8;
            const __bf16* r1 = ctb + (size_t)s_i1[kk * 64 + px] * 256 + 128 + ch * 8;
            rA[p] = *(const bf16x8*)r0;
            rB[p] = *(const bf16x8*)(r0 + 256);
            rC[p] = *(const bf16x8*)r1;
            rD[p] = *(const bf16x8*)(r1 + 256);
        }
    };
    auto combine = [&](int kk, int buf) {
#pragma unroll
        for (int p = 0; p < 4; ++p) {
            int idx = p * 256 + tid;
            int px = idx >> 4, ch = idx & 15;
            float ax = s_ax[kk * 64 + px], ay = s_ay[kk * 64 + px];
            float bx = s_bx[kk * 64 + px], by = s_by[kk * 64 + px];
            bf16x8 res;
#pragma unroll
            for (int j = 0; j < 8; ++j)
                res[j] = (__bf16)(ax * (float)rA[p][j] + ay * (float)rB[p][j] +
                                  bx * (float)rC[p][j] + by * (float)rD[p][j]);
            *(bf16x8*)&sampT[buf][px][ch * 8] = res;
        }
    };
    auto domfma = [&](int pb) {
#pragma unroll
        for (int ks = 0; ks < 4; ++ks) {
            int crow = ks * 32 + quad * 8;
#pragma unroll
            for (int nt = 0; nt < 4; ++nt) {
                bf16x8 bfrag = *(const bf16x8*)&sampT[pb][nt * 16 + col][crow];
                acc[0][nt] = __builtin_amdgcn_mfma_f32_16x16x32_bf16(
                    aBuf[ks * 2 + 0], bfrag, acc[0][nt], 0, 0, 0);
                acc[1][nt] = __builtin_amdgcn_mfma_f32_16x16x32_bf16(
                    aBuf[ks * 2 + 1], bfrag, acc[1][nt], 0, 0, 0);
            }
        }
    };

    // i -> tap kk = (k0 + i) % 9; sampT buffer = i&1.
    {
        int k1 = (k0 + 1 >= 9) ? k0 - 8 : k0 + 1;
        preload(k0);
        combine(k0, 0);
        preload(k1);
        __syncthreads();
    }
#pragma unroll
    for (int i = 0; i < 9; ++i) {
        domfma(i & 1);
        if (i < 8) {
            int kn = k0 + i + 1; if (kn >= 9) kn -= 9;
            load_a(kn);                      // refill aBuf after domfma consumed it
            combine(kn, (i + 1) & 1);
            if (i + 2 <= 8) {
                int kp = k0 + i + 2; if (kp >= 9) kp -= 9;
                preload(kp);
            }
            __syncthreads();
        }
    }

    // ================= Epilogue =================
#pragma unroll
    for (int mt = 0; mt < 2; ++mt) {
#pragma unroll
        for (int r = 0; r < 4; ++r) {
            int o = wv * 32 + mt * 16 + quad * 4 + r;
            float bv = bias[o];
#pragma unroll
            for (int nt = 0; nt < 4; ++nt)
                out[((size_t)(b * CC + o) * HH + h) * WW + nt * 16 + col] =
                    acc[mt][nt][r] + bv;
        }
    }
}

// ===========================================================================
// Fallback path (proven R5 kernels; needs only 2.8 MB ws).
// ===========================================================================
__global__ __launch_bounds__(256) void prep_kernel(
    const float* __restrict__ w, const float* __restrict__ ow,
    __bf16* __restrict__ af, __bf16* __restrict__ waf)
{
    int idx = blockIdx.x * 256 + threadIdx.x;
    if (idx < 147456) {
        int j    = idx & 7;
        int lane = (idx >> 3) & 63;
        int ks   = (idx >> 9) & 3;
        int mt2  = (idx >> 11) & 7;
        int k    = idx >> 14;
        int o = mt2 * 16 + (lane & 15);
        int c = ks * 32 + (lane >> 4) * 8 + j;
        af[idx] = (__bf16)w[(o * CC + c) * 9 + k];
    } else if (idx < 147456 + 73728) {
        int t    = idx - 147456;
        int j    = t & 7;
        int lane = (t >> 3) & 63;
        int ks   = (t >> 9) & 7;
        int mt   = (t >> 12) & 1;
        int kk   = t >> 13;
        int oc = mt * 16 + (lane & 15);
        int ic = ks * 32 + (lane >> 4) * 8 + j;
        float v = (oc < NOFF) ? ow[(oc * 256 + ic) * 9 + kk] : 0.f;
        waf[t] = (__bf16)v;
    }
}

#define TS 264
__global__ __launch_bounds__(256) void offset_conv_mfma_kernel(
    const float* __restrict__ x, const float* __restrict__ u,
    const __bf16* __restrict__ waf, const float* __restrict__ ob,
    float* __restrict__ off)
{
    const int id   = blockIdx.x;
    const int b    = id & 7;
    const int h    = id >> 3;
    const int tid  = threadIdx.x;
    const int lane = tid & 63;
    const int wv   = tid >> 6;
    const int col  = lane & 15;
    const int quad = lane >> 4;

    __shared__ __align__(16) __bf16 T[66][TS];
    {
        T[0][tid]  = (__bf16)0.f;
        T[65][tid] = (__bf16)0.f;
    }

    f32x4 acc0 = {0.f, 0.f, 0.f, 0.f};
    f32x4 acc1 = {0.f, 0.f, 0.f, 0.f};
    const bf16x8* wafp = (const bf16x8*)waf;

    for (int kh = 0; kh < 3; ++kh) {
        int y = h - 1 + kh;
        if (y < 0 || y >= HH) continue;
        __syncthreads();
        {
            int w2 = lane;
#pragma unroll
            for (int g = 0; g < 8; ++g) {
                bf16x8 pk;
#pragma unroll
                for (int j = 0; j < 8; ++j) {
                    int ic = wv * 64 + g * 8 + j;
                    float v = (ic < CC)
                        ? x[((size_t)(b * CC + ic) * HH + y) * WW + w2]
                        : u[((size_t)(b * CC + (ic - CC)) * HH + y) * WW + w2];
                    pk[j] = (__bf16)v;
                }
                *(bf16x8*)&T[w2 + 1][wv * 64 + g * 8] = pk;
            }
        }
        __syncthreads();

#pragma unroll
        for (int kw = 0; kw < 3; ++kw) {
            int kk = kh * 3 + kw;
            const __bf16* brow = &T[wv * 16 + col + kw][quad * 8];
#pragma unroll
            for (int ks = 0; ks < 8; ++ks) {
                bf16x8 bfrag = *(const bf16x8*)(brow + ks * 32);
                bf16x8 a0 = wafp[((kk * 2 + 0) * 8 + ks) * 64 + lane];
                bf16x8 a1 = wafp[((kk * 2 + 1) * 8 + ks) * 64 + lane];
                acc0 = __builtin_amdgcn_mfma_f32_16x16x32_bf16(a0, bfrag, acc0, 0, 0, 0);
                acc1 = __builtin_amdgcn_mfma_f32_16x16x32_bf16(a1, bfrag, acc1, 0, 0, 0);
            }
        }
    }

    int w2 = wv * 16 + col;
#pragma unroll
    for (int r = 0; r < 4; ++r) {
        int oc = quad * 4 + r;
        off[((size_t)(b * NOFF + oc) * HH + h) * WW + w2] = acc0[r] + ob[oc];
    }
#pragma unroll
    for (int r = 0; r < 4; ++r) {
        int oc = 16 + quad * 4 + r;
        if (oc < NOFF)
            off[((size_t)(b * NOFF + oc) * HH + h) * WW + w2] = acc1[r] + ob[oc];
    }
}

__global__ __launch_bounds__(256) void fam_main_kernel(
    const float* __restrict__ u, const __bf16* __restrict__ af,
    const float* __restrict__ bias, const float* __restrict__ off,
    float* __restrict__ out)
{
    const int id   = blockIdx.x;
    const int b    = id & 7;
    const int h    = id >> 3;
    const int tid  = threadIdx.x;
    const int lane = tid & 63;
    const int wv   = tid >> 6;
    const int col  = lane & 15;
    const int quad = lane >> 4;

    __shared__ __align__(16) __bf16 sampT[64][136];
    __shared__ float s_ax[9][64], s_ay[9][64], s_bx[9][64], s_by[9][64];
    __shared__ int   s_i0[9][64], s_i1[9][64];

    for (int t = tid; t < 9 * 64; t += 256) {
        int k  = t >> 6;
        int wq = t & 63;
        float dy = off[((size_t)(b * NOFF + 2 * k)     * HH + h) * WW + wq];
        float dx = off[((size_t)(b * NOFF + 2 * k + 1) * HH + h) * WW + wq];
        float py = (float)(h - 1 + k / 3) + dy;
        float px = (float)(wq - 1 + k % 3) + dx;
        float y0f = floorf(py), x0f = floorf(px);
        int y0 = (int)y0f, x0 = (int)x0f;
        float fy = py - y0f, fx = px - x0f;
        bool vy0 = (y0 >= 0) && (y0 < HH);
        bool vy1 = (y0 + 1 >= 0) && (y0 + 1 < HH);
        bool vx0 = (x0 >= 0) && (x0 < WW);
        bool vx1 = (x0 + 1 >= 0) && (x0 + 1 < WW);
        float w00 = (1.f - fy) * (1.f - fx) * ((vy0 && vx0) ? 1.f : 0.f);
        float w01 = (1.f - fy) * fx         * ((vy0 && vx1) ? 1.f : 0.f);
        float w10 = fy * (1.f - fx)         * ((vy1 && vx0) ? 1.f : 0.f);
        float w11 = fy * fx                 * ((vy1 && vx1) ? 1.f : 0.f);
        int y0c = min(max(y0, 0), HH - 1);
        int y1c = min(max(y0 + 1, 0), HH - 1);
        int x0c = min(max(x0, 0), WW - 1);
        int x1c = min(max(x0 + 1, 0), WW - 1);
        int xl  = min(max(x0, 0), WW - 2);
        float ax = ((x0c == xl)     ? w00 : 0.f) + ((x1c == xl)     ? w01 : 0.f);
        float ay = ((x0c == xl + 1) ? w00 : 0.f) + ((x1c == xl + 1) ? w01 : 0.f);
        float bx = ((x0c == xl)     ? w10 : 0.f) + ((x1c == xl)     ? w11 : 0.f);
        float by = ((x0c == xl + 1) ? w10 : 0.f) + ((x1c == xl + 1) ? w11 : 0.f);
        s_ax[k][wq] = ax; s_ay[k][wq] = ay;
        s_bx[k][wq] = bx; s_by[k][wq] = by;
        s_i0[k][wq] = y0c * WW + xl;
        s_i1[k][wq] = y1c * WW + xl;
    }
    __syncthreads();

    f32x4 acc[2][4];
#pragma unroll
    for (int mt = 0; mt < 2; ++mt)
#pragma unroll
        for (int nt = 0; nt < 4; ++nt) acc[mt][nt] = (f32x4){0.f, 0.f, 0.f, 0.f};

    const float* ub = u + (size_t)b * (CC * HH * WW);
    const bf16x8* afp = (const bf16x8*)af;

    for (int k = 0; k < 9; ++k) {
        {
            float ax = s_ax[k][lane], ay = s_ay[k][lane];
            float bx = s_bx[k][lane], by = s_by[k][lane];
            int   i0 = s_i0[k][lane], i1 = s_i1[k][lane];
#pragma unroll 4
            for (int g = 0; g < 4; ++g) {
                bf16x8 pk;
#pragma unroll
                for (int j = 0; j < 8; ++j) {
                    const float* up = ub + (size_t)(wv * 32 + g * 8 + j) * (HH * WW);
                    f32x2u r0 = *(const f32x2u*)(up + i0);
                    f32x2u r1 = *(const f32x2u*)(up + i1);
                    float v = ax * r0.x + ay * r0.y + bx * r1.x + by * r1.y;
                    pk[j] = (__bf16)v;
                }
                *(bf16x8*)&sampT[lane][wv * 32 + g * 8] = pk;
            }
        }
        __syncthreads();

#pragma unroll
        for (int ks = 0; ks < 4; ++ks) {
            bf16x8 a0 = afp[((k * 8 + wv * 2 + 0) * 4 + ks) * 64 + lane];
            bf16x8 a1 = afp[((k * 8 + wv * 2 + 1) * 4 + ks) * 64 + lane];
            int crow = ks * 32 + quad * 8;
#pragma unroll
            for (int nt = 0; nt < 4; ++nt) {
                bf16x8 bfrag = *(const bf16x8*)&sampT[nt * 16 + col][crow];
                acc[0][nt] = __builtin_amdgcn_mfma_f32_16x16x32_bf16(
                    a0, bfrag, acc[0][nt], 0, 0, 0);
                acc[1][nt] = __builtin_amdgcn_mfma_f32_16x16x32_bf16(
                    a1, bfrag, acc[1][nt], 0, 0, 0);
            }
        }
        __syncthreads();
    }

#pragma unroll
    for (int mt = 0; mt < 2; ++mt) {
#pragma unroll
        for (int r = 0; r < 4; ++r) {
            int o = wv * 32 + mt * 16 + quad * 4 + r;
            float bv = bias[o];
#pragma unroll
            for (int nt = 0; nt < 4; ++nt)
                out[((size_t)(b * CC + o) * HH + h) * WW + nt * 16 + col] =
                    acc[mt][nt][r] + bv;
        }
    }
}

extern "C" void kernel_launch(void* const* d_in, const int* in_sizes, int n_in,
                              void* d_out, int out_size, void* d_ws, size_t ws_size,
                              hipStream_t stream) {
    const float* x    = (const float*)d_in[0];
    const float* u    = (const float*)d_in[1];
    const float* wgt  = (const float*)d_in[2];
    const float* bias = (const float*)d_in[3];
    const float* ow   = (const float*)d_in[4];
    const float* ob   = (const float*)d_in[5];
    float* out = (float*)d_out;

    // Workspace layout (element-typed arithmetic only):
    float*  off = (float*)d_ws;                                  // 2,359,296 B (fallback only)
    __bf16* af  = (__bf16*)(off + (size_t)BB * NOFF * HH * WW);  //   294,912 B
    __bf16* waf = af + 147456;                                   //   147,456 B
    __bf16* ct  = waf + 73728;                                   // 16,777,216 B (fast path)
    const size_t need_fast = 2359296 + 294912 + 147456 + (size_t)BB * HH * WW * 256 * 2;

    if (ws_size >= need_fast) {
        hipLaunchKernelGGL(prep_transpose_kernel, dim3(1376), dim3(256), 0, stream,
                           x, u, wgt, ow, ct, af, waf);
        hipLaunchKernelGGL(fam_fused_kernel, dim3(512), dim3(256), 0, stream,
                           ct, waf, af, ob, bias, out);
    } else {
        hipLaunchKernelGGL(prep_kernel, dim3(864), dim3(256), 0, stream,
                           wgt, ow, af, waf);
        hipLaunchKernelGGL(offset_conv_mfma_kernel, dim3(512), dim3(256), 0, stream,
                           x, u, waf, ob, off);
        hipLaunchKernelGGL(fam_main_kernel, dim3(512), dim3(256), 0, stream,
                           u, af, bias, off, out);
    }
}